// Round 1
// baseline (1310.235 us; speedup 1.0000x reference)
//
#include <hip/hip_runtime.h>
#include <math.h>

// GCN 4-layer pipeline on N=100k nodes, E=3.2M edges.
// Key identities used:
//   out = dinv .* segsum( (dinv .* h')[src], dst ) + selfloop(dinv.*h')*dinv + b
//   segsum((h@W)[src]*norm) == segsum(h[src]*norm) @ W   (linearity)
// so layers 1 and 4 aggregate SCALARS; only layers 2/3 aggregate 32-wide.

__global__ void k_deg(const int* __restrict__ dst, float* __restrict__ deg, int E) {
    int e = blockIdx.x * blockDim.x + threadIdx.x;
    if (e < E) atomicAdd(&deg[dst[e]], 1.0f);
}

// in-place: dinv[i] = rsqrt(deg[i]+1)  (+1 = self loop); also sa[i] = x[i]*dinv[i]
__global__ void k_dinv(float* __restrict__ dinv, const float* __restrict__ x,
                       float* __restrict__ sa, int N) {
    int i = blockIdx.x * blockDim.x + threadIdx.x;
    if (i < N) {
        float d = rsqrtf(dinv[i] + 1.0f);
        dinv[i] = d;
        sa[i] = x[i] * d;
    }
}

__global__ void k_scatter_scalar(const int* __restrict__ src, const int* __restrict__ dst,
                                 const float* __restrict__ sa, float* __restrict__ sb, int E) {
    int e = blockIdx.x * blockDim.x + threadIdx.x;
    if (e < E) atomicAdd(&sb[dst[e]], sa[src[e]]);
}

// layer-1 expand: F0[i*32+j] = relu( (dinv[i]*(sb[i]+sa[i])) * Win[j] + bin[j] )
__global__ void k_l1(const float* __restrict__ dinv, const float* __restrict__ sa,
                     const float* __restrict__ sb, const float* __restrict__ Win,
                     const float* __restrict__ bin, float* __restrict__ F0, int N) {
    int t = blockIdx.x * blockDim.x + threadIdx.x;
    int i = t >> 5, j = t & 31;
    if (i < N) {
        float s = dinv[i] * (sb[i] + sa[i]);
        float v = s * Win[j] + bin[j];
        F0[t] = v > 0.f ? v : 0.f;
    }
}

// Fout[i*32+j] = (sum_k Fin[i*32+k] * W[k*32+j]) * dinv[i];  8 nodes / 256-thread block
__global__ void k_matvec_scale(const float* __restrict__ Fin, const float* __restrict__ W,
                               const float* __restrict__ dinv, float* __restrict__ Fout, int N) {
    __shared__ float sW[1024];
    __shared__ float sH[256];
    int t = threadIdx.x;
    #pragma unroll
    for (int r = 0; r < 4; ++r) sW[r * 256 + t] = W[r * 256 + t];
    int base = blockIdx.x * 8;
    long long gidx = (long long)base * 32 + t;
    sH[t] = (gidx < (long long)N * 32) ? Fin[gidx] : 0.f;
    __syncthreads();
    int il = t >> 5, j = t & 31;
    int i = base + il;
    if (i < N) {
        float acc = 0.f;
        #pragma unroll
        for (int k = 0; k < 32; ++k) acc += sH[il * 32 + k] * sW[k * 32 + j];
        Fout[(long long)i * 32 + j] = acc * dinv[i];
    }
}

// one thread per (edge, feature): 32 lanes share an edge -> coalesced gather + scatter
__global__ void k_scatter32(const int* __restrict__ src, const int* __restrict__ dst,
                            const float* __restrict__ G, float* __restrict__ Acc, int ET) {
    int t = blockIdx.x * blockDim.x + threadIdx.x;
    if (t < ET) {
        int e = t >> 5, j = t & 31;
        atomicAdd(&Acc[(long long)dst[e] * 32 + j], G[(long long)src[e] * 32 + j]);
    }
}

__global__ void k_combine_relu(const float* __restrict__ G, const float* __restrict__ Acc,
                               const float* __restrict__ dinv, const float* __restrict__ b,
                               float* __restrict__ Fout, int N) {
    int t = blockIdx.x * blockDim.x + threadIdx.x;
    int i = t >> 5, j = t & 31;
    if (i < N) {
        float v = dinv[i] * (Acc[t] + G[t]) + b[j];
        Fout[t] = v > 0.f ? v : 0.f;
    }
}

// sa[i] = (sum_k F[i*32+k] * Wout[k]) * dinv[i]
__global__ void k_dot_scale(const float* __restrict__ F, const float* __restrict__ Wout,
                            const float* __restrict__ dinv, float* __restrict__ sa, int N) {
    int i = blockIdx.x * blockDim.x + threadIdx.x;
    if (i < N) {
        const float4* f4 = (const float4*)(F + (long long)i * 32);
        float acc = 0.f;
        #pragma unroll
        for (int q = 0; q < 8; ++q) {
            float4 v = f4[q];
            acc += v.x * Wout[q * 4 + 0] + v.y * Wout[q * 4 + 1]
                 + v.z * Wout[q * 4 + 2] + v.w * Wout[q * 4 + 3];
        }
        sa[i] = acc * dinv[i];
    }
}

__global__ void k_final(const float* __restrict__ dinv, const float* __restrict__ sa,
                        const float* __restrict__ sb, const float* __restrict__ bout,
                        float* __restrict__ out, int N) {
    int i = blockIdx.x * blockDim.x + threadIdx.x;
    if (i < N) {
        float z = dinv[i] * (sb[i] + sa[i]) + bout[0];
        out[i] = 1.0f / (1.0f + expf(-z));
    }
}

extern "C" void kernel_launch(void* const* d_in, const int* in_sizes, int n_in,
                              void* d_out, int out_size, void* d_ws, size_t ws_size,
                              hipStream_t stream) {
    const float* x    = (const float*)d_in[0];
    const int*   ei   = (const int*)  d_in[1];
    const float* Win  = (const float*)d_in[2];
    const float* bin  = (const float*)d_in[3];
    const float* Wmid = (const float*)d_in[4];
    const float* bmid = (const float*)d_in[5];
    const float* Wout = (const float*)d_in[6];
    const float* bout = (const float*)d_in[7];
    float* out = (float*)d_out;

    int N = in_sizes[0];
    int E = in_sizes[1] / 2;
    const int* src = ei;        // edge_index[0]
    const int* dst = ei + E;    // edge_index[1]

    float* ws   = (float*)d_ws;
    float* dinv = ws;                              // N
    float* sa   = ws + (size_t)N;                  // N
    float* sb   = ws + 2 * (size_t)N;              // N
    float* F0   = ws + 3 * (size_t)N;              // 32N
    float* F1   = F0 + 32 * (size_t)N;             // 32N
    float* F2   = F1 + 32 * (size_t)N;             // 32N

    const int B = 256;
    int gN   = (N + B - 1) / B;
    int gE   = (E + B - 1) / B;
    int ET   = E * 32;                 // 102.4M, fits int
    int NT   = N * 32;
    int gN32 = (NT + B - 1) / B;
    int gE32 = (ET + B - 1) / B;
    int gMV  = (N + 7) / 8;

    // degree -> dinv, and layer-1 scalar pre-scale
    hipMemsetAsync(dinv, 0, (size_t)N * 4, stream);
    k_deg<<<gE, B, 0, stream>>>(dst, dinv, E);
    k_dinv<<<gN, B, 0, stream>>>(dinv, x, sa, N);

    // layer 1 (scalar aggregate, then expand by W_in)
    hipMemsetAsync(sb, 0, (size_t)N * 4, stream);
    k_scatter_scalar<<<gE, B, 0, stream>>>(src, dst, sa, sb, E);
    k_l1<<<gN32, B, 0, stream>>>(dinv, sa, sb, Win, bin, F0, N);

    // layer 2
    k_matvec_scale<<<gMV, B, 0, stream>>>(F0, Wmid, dinv, F1, N);
    hipMemsetAsync(F2, 0, (size_t)NT * 4, stream);
    k_scatter32<<<gE32, B, 0, stream>>>(src, dst, F1, F2, ET);
    k_combine_relu<<<gN32, B, 0, stream>>>(F1, F2, dinv, bmid, F0, N);

    // layer 3
    k_matvec_scale<<<gMV, B, 0, stream>>>(F0, Wmid, dinv, F1, N);
    hipMemsetAsync(F2, 0, (size_t)NT * 4, stream);
    k_scatter32<<<gE32, B, 0, stream>>>(src, dst, F1, F2, ET);
    k_combine_relu<<<gN32, B, 0, stream>>>(F1, F2, dinv, bmid, F0, N);

    // layer 4 (contract with W_out first, then scalar aggregate)
    k_dot_scale<<<gN, B, 0, stream>>>(F0, Wout, dinv, sa, N);
    hipMemsetAsync(sb, 0, (size_t)N * 4, stream);
    k_scatter_scalar<<<gE, B, 0, stream>>>(src, dst, sa, sb, E);
    k_final<<<gN, B, 0, stream>>>(dinv, sa, sb, bout, out, N);
}

// Round 2
// 663.635 us; speedup vs baseline: 1.9743x; 1.9743x over previous
//
#include <hip/hip_runtime.h>
#include <math.h>

// GCN 4-layer, N=100k, E=3.2M. Round 2: no float atomics.
// Build dst-sorted CSR once per launch; aggregations are gather+register-sum.
// Identities: norm factorizes (dinv pre/post scale); matmul commutes with
// segment-sum, so layers 1/4 aggregate scalars.

#define BLK 256

__global__ void k_hist(const int* __restrict__ dst, int* __restrict__ cnt, int E) {
    int e = blockIdx.x * blockDim.x + threadIdx.x;
    if (e < E) atomicAdd(&cnt[dst[e]], 1);
}

// block-local exclusive scan of cnt -> rs, block totals -> partials
__global__ void k_scan1(const int* __restrict__ cnt, int* __restrict__ rs,
                        int* __restrict__ partials, int N) {
    __shared__ int sh[BLK];
    int t = threadIdx.x;
    int i = blockIdx.x * BLK + t;
    int v = (i < N) ? cnt[i] : 0;
    sh[t] = v;
    __syncthreads();
    // Hillis-Steele inclusive scan
    for (int off = 1; off < BLK; off <<= 1) {
        int add = (t >= off) ? sh[t - off] : 0;
        __syncthreads();
        sh[t] += add;
        __syncthreads();
    }
    if (i < N) rs[i] = sh[t] - v;           // exclusive
    if (t == BLK - 1) partials[blockIdx.x] = sh[t];
}

// single-block scan of partials (exclusive, in place)
__global__ void k_scan2(int* __restrict__ partials, int nb) {
    __shared__ int sh[BLK];
    int t = threadIdx.x;
    int carry = 0;
    for (int base = 0; base < nb; base += BLK) {
        int i = base + t;
        int v = (i < nb) ? partials[i] : 0;
        sh[t] = v;
        __syncthreads();
        for (int off = 1; off < BLK; off <<= 1) {
            int add = (t >= off) ? sh[t - off] : 0;
            __syncthreads();
            sh[t] += add;
            __syncthreads();
        }
        if (i < nb) partials[i] = sh[t] - v + carry;
        carry += sh[BLK - 1];
        __syncthreads();
    }
}

// add block offsets; also dinv = rsqrt(deg+1), sa = x*dinv; rs[N] = E
__global__ void k_scan3(int* __restrict__ rs, const int* __restrict__ partials,
                        const int* __restrict__ cnt, const float* __restrict__ x,
                        float* __restrict__ dinv, float* __restrict__ sa, int N, int E) {
    int i = blockIdx.x * blockDim.x + threadIdx.x;
    if (i < N) {
        rs[i] += partials[i >> 8];
        float d = rsqrtf((float)cnt[i] + 1.0f);
        dinv[i] = d;
        sa[i] = x[i] * d;
    }
    if (i == 0) rs[N] = E;
}

// cursor (cnt, re-zeroed) -> scatter src ids into dst-sorted order
__global__ void k_fill(const int* __restrict__ src, const int* __restrict__ dst,
                       const int* __restrict__ rs, int* __restrict__ cur,
                       int* __restrict__ ss, int E) {
    int e = blockIdx.x * blockDim.x + threadIdx.x;
    if (e < E) {
        int d = dst[e];
        int p = atomicAdd(&cur[d], 1);
        ss[rs[d] + p] = src[e];
    }
}

// layer 1: scalar gather-reduce + expand by W_in, fused
__global__ void k_l1agg(const int* __restrict__ rs, const int* __restrict__ ss,
                        const float* __restrict__ sa, const float* __restrict__ dinv,
                        const float* __restrict__ Win, const float* __restrict__ bin,
                        float* __restrict__ F0, int N) {
    int t = blockIdx.x * blockDim.x + threadIdx.x;
    int i = t >> 5, l = t & 31;
    if (i >= N) return;
    int beg = rs[i], end = rs[i + 1];
    float s = 0.f;
    for (int e = beg + l; e < end; e += 32) s += sa[ss[e]];
    #pragma unroll
    for (int m = 16; m; m >>= 1) s += __shfl_xor(s, m, 32);
    float h = dinv[i] * (s + sa[i]);          // self loop + post-scale
    float v = h * Win[l] + bin[l];
    F0[t] = v > 0.f ? v : 0.f;
}

// G = (F @ W) * dinv, 8 nodes per 256-thread block
__global__ void k_matvec_scale(const float* __restrict__ Fin, const float* __restrict__ W,
                               const float* __restrict__ dinv, float* __restrict__ Fout, int N) {
    __shared__ float sW[1024];
    __shared__ float sH[256];
    int t = threadIdx.x;
    #pragma unroll
    for (int r = 0; r < 4; ++r) sW[r * 256 + t] = W[r * 256 + t];
    int base = blockIdx.x * 8;
    long long gidx = (long long)base * 32 + t;
    sH[t] = (gidx < (long long)N * 32) ? Fin[gidx] : 0.f;
    __syncthreads();
    int il = t >> 5, j = t & 31;
    int i = base + il;
    if (i < N) {
        float acc = 0.f;
        #pragma unroll
        for (int k = 0; k < 32; ++k) acc += sH[il * 32 + k] * sW[k * 32 + j];
        Fout[(long long)i * 32 + j] = acc * dinv[i];
    }
}

// wide aggregate: 32-lane group per node, lane = feature; fused combine+relu
__global__ void k_agg32(const int* __restrict__ rs, const int* __restrict__ ss,
                        const float* __restrict__ G, const float* __restrict__ dinv,
                        const float* __restrict__ b, float* __restrict__ Fout, int N) {
    int t = blockIdx.x * blockDim.x + threadIdx.x;
    int i = t >> 5, j = t & 31;
    if (i >= N) return;
    int beg = rs[i], end = rs[i + 1];
    float acc = G[(long long)i * 32 + j];     // self loop
    int e = beg;
    for (; e + 4 <= end; e += 4) {
        int s0 = ss[e], s1 = ss[e + 1], s2 = ss[e + 2], s3 = ss[e + 3];
        float g0 = G[(long long)s0 * 32 + j];
        float g1 = G[(long long)s1 * 32 + j];
        float g2 = G[(long long)s2 * 32 + j];
        float g3 = G[(long long)s3 * 32 + j];
        acc += (g0 + g1) + (g2 + g3);
    }
    for (; e < end; ++e) acc += G[(long long)ss[e] * 32 + j];
    float v = dinv[i] * acc + b[j];
    Fout[t] = v > 0.f ? v : 0.f;
}

// sa2 = (F . Wout) * dinv
__global__ void k_dot_scale(const float* __restrict__ F, const float* __restrict__ Wout,
                            const float* __restrict__ dinv, float* __restrict__ sa, int N) {
    int i = blockIdx.x * blockDim.x + threadIdx.x;
    if (i < N) {
        const float4* f4 = (const float4*)(F + (long long)i * 32);
        float acc = 0.f;
        #pragma unroll
        for (int q = 0; q < 8; ++q) {
            float4 v = f4[q];
            acc += v.x * Wout[q * 4 + 0] + v.y * Wout[q * 4 + 1]
                 + v.z * Wout[q * 4 + 2] + v.w * Wout[q * 4 + 3];
        }
        sa[i] = acc * dinv[i];
    }
}

// layer 4: scalar gather-reduce + sigmoid, fused
__global__ void k_final_agg(const int* __restrict__ rs, const int* __restrict__ ss,
                            const float* __restrict__ sa, const float* __restrict__ dinv,
                            const float* __restrict__ bout, float* __restrict__ out, int N) {
    int t = blockIdx.x * blockDim.x + threadIdx.x;
    int i = t >> 5, l = t & 31;
    if (i >= N) return;
    int beg = rs[i], end = rs[i + 1];
    float s = 0.f;
    for (int e = beg + l; e < end; e += 32) s += sa[ss[e]];
    #pragma unroll
    for (int m = 16; m; m >>= 1) s += __shfl_xor(s, m, 32);
    if (l == 0) {
        float z = dinv[i] * (s + sa[i]) + bout[0];
        out[i] = 1.0f / (1.0f + expf(-z));
    }
}

extern "C" void kernel_launch(void* const* d_in, const int* in_sizes, int n_in,
                              void* d_out, int out_size, void* d_ws, size_t ws_size,
                              hipStream_t stream) {
    const float* x    = (const float*)d_in[0];
    const int*   ei   = (const int*)  d_in[1];
    const float* Win  = (const float*)d_in[2];
    const float* bin  = (const float*)d_in[3];
    const float* Wmid = (const float*)d_in[4];
    const float* bmid = (const float*)d_in[5];
    const float* Wout = (const float*)d_in[6];
    const float* bout = (const float*)d_in[7];
    float* out = (float*)d_out;

    int N = in_sizes[0];
    int E = in_sizes[1] / 2;
    const int* src = ei;
    const int* dst = ei + E;

    // workspace layout
    int* cnt      = (int*)d_ws;                    // N (histogram, then cursor)
    int* rs       = cnt + N;                       // N+1
    int* partials = rs + N + 1;                    // 512
    int* ss       = partials + 512;                // E
    float* fbase  = (float*)(ss + E);
    float* dinv = fbase;                           // N
    float* sa   = fbase + (size_t)N;               // N
    float* F0   = fbase + 2 * (size_t)N;           // 32N
    float* F1   = F0 + 32 * (size_t)N;             // 32N

    int gN   = (N + BLK - 1) / BLK;
    int gE   = (E + BLK - 1) / BLK;
    int NT   = N * 32;
    int gN32 = (NT + BLK - 1) / BLK;
    int gMV  = (N + 7) / 8;
    int nb   = gN;   // scan blocks

    // CSR build + dinv
    hipMemsetAsync(cnt, 0, (size_t)N * 4, stream);
    k_hist<<<gE, BLK, 0, stream>>>(dst, cnt, E);
    k_scan1<<<nb, BLK, 0, stream>>>(cnt, rs, partials, N);
    k_scan2<<<1, BLK, 0, stream>>>(partials, nb);
    k_scan3<<<gN, BLK, 0, stream>>>(rs, partials, cnt, x, dinv, sa, N, E);
    hipMemsetAsync(cnt, 0, (size_t)N * 4, stream);
    k_fill<<<gE, BLK, 0, stream>>>(src, dst, rs, cnt, ss, E);

    // layer 1 (scalar aggregate fused with expand)
    k_l1agg<<<gN32, BLK, 0, stream>>>(rs, ss, sa, dinv, Win, bin, F0, N);

    // layer 2
    k_matvec_scale<<<gMV, BLK, 0, stream>>>(F0, Wmid, dinv, F1, N);
    k_agg32<<<gN32, BLK, 0, stream>>>(rs, ss, F1, dinv, bmid, F0, N);

    // layer 3
    k_matvec_scale<<<gMV, BLK, 0, stream>>>(F0, Wmid, dinv, F1, N);
    k_agg32<<<gN32, BLK, 0, stream>>>(rs, ss, F1, dinv, bmid, F0, N);

    // layer 4 (contract then scalar aggregate + sigmoid)
    k_dot_scale<<<gN, BLK, 0, stream>>>(F0, Wout, dinv, sa, N);
    k_final_agg<<<gN32, BLK, 0, stream>>>(rs, ss, sa, dinv, bout, out, N);
}

// Round 3
// 512.740 us; speedup vs baseline: 2.5554x; 1.2943x over previous
//
#include <hip/hip_runtime.h>
#include <math.h>

// GCN 4-layer, N=100k, E=3.2M. Round 3:
//  - CSR build via 2-phase bucket sort (no 197MB scattered-write fill,
//    no separate hist/scan kernels).
//  - Wide aggregation uses float4 lanes: 4 edges per VMEM instruction.
// Identities: norm factorizes (dinv pre/post scale); matmul commutes with
// segment-sum, so layers 1/4 aggregate scalars.

#define BLK 256
#define CAP 768          // per-(bucket,partition) capacity; mean 512, +11 sigma

// phase 1: append packed (src | localdst<<17) into bucket (dst>>7), partition blockIdx&7
__global__ void k_bucket(const int* __restrict__ src, const int* __restrict__ dst,
                         int* __restrict__ cur, int* __restrict__ bkt, int E) {
    int e = blockIdx.x * BLK + threadIdx.x;
    int p = blockIdx.x & 7;
    if (e < E) {
        int d = dst[e];
        int s = src[e];
        int b = d >> 7;
        int idx = atomicAdd(&cur[b * 8 + p], 1);
        bkt[(b * 8 + p) * CAP + idx] = s | ((d & 127) << 17);
    }
}

// exclusive scan of per-bucket totals (sum over 8 partitions); single block
__global__ void k_bucket_scan(const int* __restrict__ cur, int* __restrict__ base, int NB) {
    __shared__ int sh[BLK];
    int t = threadIdx.x;
    int carry = 0;
    for (int s0 = 0; s0 < NB; s0 += BLK) {
        int i = s0 + t;
        int v = 0;
        if (i < NB) {
            const int* c = &cur[i * 8];
            v = c[0] + c[1] + c[2] + c[3] + c[4] + c[5] + c[6] + c[7];
        }
        sh[t] = v;
        __syncthreads();
        for (int o = 1; o < BLK; o <<= 1) {
            int a = (t >= o) ? sh[t - o] : 0;
            __syncthreads();
            sh[t] += a;
            __syncthreads();
        }
        if (i < NB) base[i] = sh[t] - v + carry;
        carry += sh[BLK - 1];
        __syncthreads();
    }
}

// phase 2: block per bucket -> LDS hist, LDS scan, contiguous scatter into ss;
// also writes rs, dinv, sa
__global__ void k_build(const int* __restrict__ cur, const int* __restrict__ bkt,
                        const int* __restrict__ base, const float* __restrict__ x,
                        int* __restrict__ rs, int* __restrict__ ss,
                        float* __restrict__ dinv, float* __restrict__ sa,
                        int N, int E) {
    __shared__ int cnt[128], lrs[128], lcur[128], szs[8];
    int b = blockIdx.x, t = threadIdx.x;
    int node_base = b << 7;
    if (t < 128) cnt[t] = 0;
    if (t < 8) szs[t] = cur[b * 8 + t];
    __syncthreads();
    for (int p = 0; p < 8; ++p) {
        int sz = szs[p];
        const int* q = &bkt[(b * 8 + p) * CAP];
        for (int k = t; k < sz; k += BLK) atomicAdd(&cnt[(q[k] >> 17) & 127], 1);
    }
    __syncthreads();
    if (t < 128) lrs[t] = cnt[t];
    __syncthreads();
    for (int o = 1; o < 128; o <<= 1) {
        int a = (t >= o && t < 128) ? lrs[t - o] : 0;
        __syncthreads();
        if (t < 128) lrs[t] += a;
        __syncthreads();
    }
    int gb = base[b];
    if (t < 128) {
        int ex = lrs[t] - cnt[t];          // exclusive local scan
        lcur[t] = gb + ex;                  // global cursor
        int i = node_base + t;
        if (i < N) {
            rs[i] = gb + ex;
            float d = rsqrtf((float)cnt[t] + 1.0f);
            dinv[i] = d;
            sa[i] = x[i] * d;
        }
    }
    if (b == 0 && t == 0) rs[N] = E;
    __syncthreads();
    for (int p = 0; p < 8; ++p) {
        int sz = szs[p];
        const int* q = &bkt[(b * 8 + p) * CAP];
        for (int k = t; k < sz; k += BLK) {
            int v = q[k];
            int ld = (v >> 17) & 127;
            int pos = atomicAdd(&lcur[ld], 1);
            ss[pos] = v & 0x1FFFF;
        }
    }
}

// layer 1: scalar gather-reduce + expand by W_in, fused
__global__ void k_l1agg(const int* __restrict__ rs, const int* __restrict__ ss,
                        const float* __restrict__ sa, const float* __restrict__ dinv,
                        const float* __restrict__ Win, const float* __restrict__ bin,
                        float* __restrict__ F0, int N) {
    int t = blockIdx.x * blockDim.x + threadIdx.x;
    int i = t >> 5, l = t & 31;
    if (i >= N) return;
    int beg = rs[i], end = rs[i + 1];
    float s = 0.f;
    for (int e = beg + l; e < end; e += 32) s += sa[ss[e]];
    #pragma unroll
    for (int m = 16; m; m >>= 1) s += __shfl_xor(s, m, 32);
    float h = dinv[i] * (s + sa[i]);
    float v = h * Win[l] + bin[l];
    F0[t] = v > 0.f ? v : 0.f;
}

// G = (F @ W) * dinv, 8 nodes per 256-thread block
__global__ void k_matvec_scale(const float* __restrict__ Fin, const float* __restrict__ W,
                               const float* __restrict__ dinv, float* __restrict__ Fout, int N) {
    __shared__ float sW[1024];
    __shared__ float sH[256];
    int t = threadIdx.x;
    #pragma unroll
    for (int r = 0; r < 4; ++r) sW[r * 256 + t] = W[r * 256 + t];
    int base = blockIdx.x * 8;
    long long gidx = (long long)base * 32 + t;
    sH[t] = (gidx < (long long)N * 32) ? Fin[gidx] : 0.f;
    __syncthreads();
    int il = t >> 5, j = t & 31;
    int i = base + il;
    if (i < N) {
        float acc = 0.f;
        #pragma unroll
        for (int k = 0; k < 32; ++k) acc += sH[il * 32 + k] * sW[k * 32 + j];
        Fout[(long long)i * 32 + j] = acc * dinv[i];
    }
}

// wide aggregate, float4 lanes: 32-lane group per node; sub = lane>>3 handles
// every 4th edge; each lane loads float4 (4 features). 8 edges in flight.
__global__ void k_agg32v4(const int* __restrict__ rs, const int* __restrict__ ss,
                          const float4* __restrict__ G4, const float* __restrict__ dinv,
                          const float* __restrict__ b, float4* __restrict__ Fout4, int N) {
    int t = blockIdx.x * blockDim.x + threadIdx.x;
    int g = t >> 5;
    if (g >= N) return;
    int lane = t & 31, sub = lane >> 3, fl = lane & 7;
    int beg = rs[g], end = rs[g + 1];
    float4 acc;
    if (sub == 0) acc = G4[(long long)g * 8 + fl];        // self loop
    else { acc.x = 0.f; acc.y = 0.f; acc.z = 0.f; acc.w = 0.f; }
    int e = beg + sub;
    for (; e + 4 < end; e += 8) {
        int s0 = ss[e], s1 = ss[e + 4];
        float4 g0 = G4[(long long)s0 * 8 + fl];
        float4 g1 = G4[(long long)s1 * 8 + fl];
        acc.x += g0.x + g1.x; acc.y += g0.y + g1.y;
        acc.z += g0.z + g1.z; acc.w += g0.w + g1.w;
    }
    for (; e < end; e += 4) {
        int s0 = ss[e];
        float4 g0 = G4[(long long)s0 * 8 + fl];
        acc.x += g0.x; acc.y += g0.y; acc.z += g0.z; acc.w += g0.w;
    }
    #pragma unroll
    for (int m = 8; m <= 16; m <<= 1) {
        acc.x += __shfl_xor(acc.x, m);
        acc.y += __shfl_xor(acc.y, m);
        acc.z += __shfl_xor(acc.z, m);
        acc.w += __shfl_xor(acc.w, m);
    }
    if (sub == 0) {
        float4 bb = ((const float4*)b)[fl];
        float d = dinv[g];
        float4 v;
        v.x = d * acc.x + bb.x; v.y = d * acc.y + bb.y;
        v.z = d * acc.z + bb.z; v.w = d * acc.w + bb.w;
        v.x = v.x > 0.f ? v.x : 0.f; v.y = v.y > 0.f ? v.y : 0.f;
        v.z = v.z > 0.f ? v.z : 0.f; v.w = v.w > 0.f ? v.w : 0.f;
        Fout4[(long long)g * 8 + fl] = v;
    }
}

// sa2 = (F . Wout) * dinv
__global__ void k_dot_scale(const float* __restrict__ F, const float* __restrict__ Wout,
                            const float* __restrict__ dinv, float* __restrict__ sa, int N) {
    int i = blockIdx.x * blockDim.x + threadIdx.x;
    if (i < N) {
        const float4* f4 = (const float4*)(F + (long long)i * 32);
        float acc = 0.f;
        #pragma unroll
        for (int q = 0; q < 8; ++q) {
            float4 v = f4[q];
            acc += v.x * Wout[q * 4 + 0] + v.y * Wout[q * 4 + 1]
                 + v.z * Wout[q * 4 + 2] + v.w * Wout[q * 4 + 3];
        }
        sa[i] = acc * dinv[i];
    }
}

// layer 4: scalar gather-reduce + sigmoid, fused
__global__ void k_final_agg(const int* __restrict__ rs, const int* __restrict__ ss,
                            const float* __restrict__ sa, const float* __restrict__ dinv,
                            const float* __restrict__ bout, float* __restrict__ out, int N) {
    int t = blockIdx.x * blockDim.x + threadIdx.x;
    int i = t >> 5, l = t & 31;
    if (i >= N) return;
    int beg = rs[i], end = rs[i + 1];
    float s = 0.f;
    for (int e = beg + l; e < end; e += 32) s += sa[ss[e]];
    #pragma unroll
    for (int m = 16; m; m >>= 1) s += __shfl_xor(s, m, 32);
    if (l == 0) {
        float z = dinv[i] * (s + sa[i]) + bout[0];
        out[i] = 1.0f / (1.0f + expf(-z));
    }
}

extern "C" void kernel_launch(void* const* d_in, const int* in_sizes, int n_in,
                              void* d_out, int out_size, void* d_ws, size_t ws_size,
                              hipStream_t stream) {
    const float* x    = (const float*)d_in[0];
    const int*   ei   = (const int*)  d_in[1];
    const float* Win  = (const float*)d_in[2];
    const float* bin  = (const float*)d_in[3];
    const float* Wmid = (const float*)d_in[4];
    const float* bmid = (const float*)d_in[5];
    const float* Wout = (const float*)d_in[6];
    const float* bout = (const float*)d_in[7];
    float* out = (float*)d_out;

    int N = in_sizes[0];
    int E = in_sizes[1] / 2;
    const int* src = ei;
    const int* dst = ei + E;

    int NB = (N + 127) >> 7;                       // buckets of 128 nodes

    // workspace layout (bkt aliases F0/F1 region: build finishes before F0 written)
    int* cur   = (int*)d_ws;                       // NB*8 (pad 8192)
    int* base  = cur + 8192;                       // NB   (pad 1024)
    int* rs    = base + 1024;                      // N+1
    int* ss    = rs + N + 1;                       // E
    float* dinv = (float*)(ss + E);                // N
    float* sa   = dinv + N;                        // N
    float* F0   = sa + N;                          // 32N  (aliases bkt)
    float* F1   = F0 + 32 * (size_t)N;             // 32N
    int* bkt    = (int*)F0;                        // NB*8*CAP ints (19.2MB < 25.6MB)

    int gN   = (N + BLK - 1) / BLK;
    int gE   = (E + BLK - 1) / BLK;
    int NT   = N * 32;
    int gN32 = (NT + BLK - 1) / BLK;
    int gMV  = (N + 7) / 8;

    // CSR build: bucket-append -> scan -> per-bucket hist+scan+scatter
    hipMemsetAsync(cur, 0, (size_t)NB * 8 * 4, stream);
    k_bucket<<<gE, BLK, 0, stream>>>(src, dst, cur, bkt, E);
    k_bucket_scan<<<1, BLK, 0, stream>>>(cur, base, NB);
    k_build<<<NB, BLK, 0, stream>>>(cur, bkt, base, x, rs, ss, dinv, sa, N, E);

    // layer 1
    k_l1agg<<<gN32, BLK, 0, stream>>>(rs, ss, sa, dinv, Win, bin, F0, N);

    // layer 2
    k_matvec_scale<<<gMV, BLK, 0, stream>>>(F0, Wmid, dinv, F1, N);
    k_agg32v4<<<gN32, BLK, 0, stream>>>(rs, ss, (const float4*)F1, dinv, bmid, (float4*)F0, N);

    // layer 3
    k_matvec_scale<<<gMV, BLK, 0, stream>>>(F0, Wmid, dinv, F1, N);
    k_agg32v4<<<gN32, BLK, 0, stream>>>(rs, ss, (const float4*)F1, dinv, bmid, (float4*)F0, N);

    // layer 4
    k_dot_scale<<<gN, BLK, 0, stream>>>(F0, Wout, dinv, sa, N);
    k_final_agg<<<gN32, BLK, 0, stream>>>(rs, ss, sa, dinv, bout, out, N);
}